// Round 6
// baseline (276.648 us; speedup 1.0000x reference)
//
#include <hip/hip_runtime.h>

#define SS 8
#define NN 5000
#define NNSQ 25000000
#define DD 128
#define RB 8          // rows per block
#define JS 4          // column splits (partials)
#define JT 128        // tile columns
#define TPB 10        // tiles per block
#define RG 625        // row groups

typedef float f4 __attribute__((ext_vector_type(4)));

typedef const __attribute__((address_space(1))) void glb_void;
typedef __attribute__((address_space(3))) void lds_void;

__device__ __forceinline__ void gld_lds16(const void* g, void* l) {
    __builtin_amdgcn_global_load_lds((glb_void*)g, (lds_void*)l, 16, 0, 0);
}

#define VMCNT9  asm volatile("s_waitcnt vmcnt(9)" ::: "memory")
#define VMCNT0  asm volatile("s_waitcnt vmcnt(0)" ::: "memory")
#define LGKM0   asm volatile("s_waitcnt lgkmcnt(0)" ::: "memory")
#define SB0     __builtin_amdgcn_sched_barrier(0)

__global__ __launch_bounds__(256, 2)
void diffuse_spmm(const float* __restrict__ theta,
                  const float* __restrict__ Tm,
                  const float* __restrict__ x,
                  const float* __restrict__ am,
                  float* __restrict__ ws)
{
    // stg[p]: 8 T-slices x 8 rows x 128 cols (32 KB each, double-buffered)
    __shared__ float stg[2][SS * RB * 128];
    __shared__ float qv[2][RB * 128];          // double-buffered q tile

    const int t    = threadIdx.x;
    const int wid  = t >> 6;
    const int lane = t & 63;
    const int rg   = blockIdx.x % RG;
    const int js   = blockIdx.x / RG;
    const int i0   = rg * RB;
    const int tile0 = js * TPB;

    // stage/q-compute mapping: thread touches only rows its OWN wave DMA'd
    const int ar = (wid << 1) + (lane >> 5);   // row 0..7
    const int aj = (lane & 31) << 2;           // col quad offset 0..124
    // Phase B mapping
    const int h  = t >> 5;                     // j-subgroup (16 consecutive cols)
    const int d0 = (t & 31) << 2;

    float th[SS];
#pragma unroll
    for (int s = 0; s < SS; ++s) th[s] = theta[s];

    // DMA tile (rel m) T rows into stg[m&1]. 0 VGPR cost; wave-uniform LDS base.
    auto stage_dma = [&](int m) {
        const int j = (tile0 + m) * JT + aj;
        if (j < NN) {
            const size_t goff = (size_t)(i0 + ar) * NN + j;
#pragma unroll
            for (int s = 0; s < SS; ++s)
                gld_lds16(Tm + (size_t)s * NNSQ + goff,
                          &stg[m & 1][s * (RB * 128) + (wid << 1) * 128]);
        }
    };

    auto aload = [&](int m) -> f4 {
        const int j = (tile0 + m) * JT + aj;
        f4 v = (f4)(0.0f);
        if (j < NN) v = *(const f4*)(am + (size_t)(i0 + ar) * NN + j);
        return v;
    };

    // q-compute tile (rel m) -> qv[m&1]; reads only own-wave staged rows
    auto qcompute = [&](int m, f4 sa) {
        const int j = (tile0 + m) * JT + aj;
        const int lbase = ar * 128 + aj;
        f4 ssum = (*(const f4*)&stg[m & 1][0 * (RB * 128) + lbase]) * th[0];
#pragma unroll
        for (int s = 1; s < SS; ++s)
            ssum += (*(const f4*)&stg[m & 1][s * (RB * 128) + lbase]) * th[s];
        f4 q = sa * ssum;
        if (j >= NN) q = (f4)(0.0f);
        *(f4*)&qv[m & 1][ar * 128 + aj] = q;
    };

    f4 acc[RB];
#pragma unroll
    for (int r = 0; r < RB; ++r) acc[r] = (f4)(0.0f);

    // ---- prologue: DMA tile0 -> buf0, a(0), DMA tile1 -> buf1 ----
    stage_dma(0);
    f4 a0 = aload(0);
    SB0;
    stage_dma(1);
    SB0;
    VMCNT9;             // tile0 batch + a0 done; tile1 batch in flight
    SB0;
    qcompute(0, a0);
    LGKM0;
    __builtin_amdgcn_s_barrier();

    for (int k = 0; k < TPB; ++k) {
        // ---- x loads for tile k + a for tile k+1: FIRST into the vmcnt FIFO ----
        f4 xv[16];                             // static indexing only
        {
            const int jb = (tile0 + k) * JT + (h << 4);
#pragma unroll
            for (int q = 0; q < 16; ++q) {
                const int j = jb + q;
                if (j < NN) xv[q] = *(const f4*)(x + (size_t)j * DD + d0);
                else        xv[q] = (f4)(0.0f);
            }
        }
        f4 sa = (f4)(0.0f);
        if (k + 1 < TPB) sa = aload(k + 1);
        SB0;
        // ---- DMA tile k+2: LAST into the FIFO (stays in flight across barrier) ----
        if (k + 2 < TPB) stage_dma(k + 2);
        SB0;

        // ---- Phase B on tile k: acc[r] += qv[r][jj] * x[jj][d0..d0+3] ----
        // consuming xv waits vmcnt(9) at worst -> k+2 DMA never drained here
        const float* qp = &qv[k & 1][0];
#pragma unroll
        for (int qc = 0; qc < 4; ++qc) {
#pragma unroll
            for (int r = 0; r < RB; ++r) {
                f4 q = *(const f4*)&qp[r * 128 + (h << 4) + (qc << 2)];
                acc[r] += q.x * xv[qc * 4 + 0];
                acc[r] += q.y * xv[qc * 4 + 1];
                acc[r] += q.z * xv[qc * 4 + 2];
                acc[r] += q.w * xv[qc * 4 + 3];
            }
        }

        if (k + 1 < TPB) {
            // wait tile k+1's batch (issued one full body ago); keep k+2 in flight
            if (k + 2 < TPB) { VMCNT9; } else { VMCNT0; }
            SB0;
            qcompute(k + 1, sa);
            LGKM0;
            __builtin_amdgcn_s_barrier();      // publish qv; does NOT drain vmcnt
        }
    }

    // ---- epilogue: reduce h-pairs in wave, then cross-wave via LDS ----
#pragma unroll
    for (int r = 0; r < RB; ++r)
#pragma unroll
        for (int c = 0; c < 4; ++c)
            acc[r][c] += __shfl_xor(acc[r][c], 32);

    float* red = &stg[0][0];                   // alias dead stage buffer (12 KB)
    __syncthreads();                           // loop done; full drain is fine here
    if (wid > 0 && lane < 32) {
#pragma unroll
        for (int r = 0; r < RB; ++r)
            *(f4*)&red[((wid - 1) * RB + r) * 128 + d0] = acc[r];
    }
    __syncthreads();
    if (wid == 0 && lane < 32) {
#pragma unroll
        for (int r = 0; r < RB; ++r) {
            f4 v = acc[r];
#pragma unroll
            for (int p = 0; p < 3; ++p)
                v += *(const f4*)&red[(p * RB + r) * 128 + d0];
            *(f4*)&ws[(((size_t)js * RG + rg) * RB + r) * DD + d0] = v;
        }
    }
}

// Kernel 2: out[i,:] = PReLU(sum_js partial[js][i,:]) @ W^T + b
__global__ __launch_bounds__(256, 2)
void prelu_linear(const float* __restrict__ alpha,
                  const float* __restrict__ W,
                  const float* __restrict__ b,
                  const float* __restrict__ ws,
                  float* __restrict__ out)
{
    __shared__ float Wt[128 * 129];
    __shared__ float p[16 * 128];
    const int t  = threadIdx.x;
    const int i0 = blockIdx.x * 16;

#pragma unroll
    for (int it = 0; it < 16; ++it) {
        int f  = (it * 256 + t) * 4;
        int d  = f >> 7;
        int kk = f & 127;
        f4 w4 = *(const f4*)(W + f);
        Wt[(kk + 0) * 129 + d] = w4.x;
        Wt[(kk + 1) * 129 + d] = w4.y;
        Wt[(kk + 2) * 129 + d] = w4.z;
        Wt[(kk + 3) * 129 + d] = w4.w;
    }

#pragma unroll
    for (int it = 0; it < 2; ++it) {
        int fi  = it * 256 + t;
        int row = i0 + (fi >> 5);
        int dc  = (fi & 31) << 2;
        if (row < NN) {
            size_t base = (size_t)row * DD + dc;
            f4 v = *(const f4*)(ws + base);
            v += *(const f4*)(ws + base + (size_t)1 * RG * RB * DD);
            v += *(const f4*)(ws + base + (size_t)2 * RG * RB * DD);
            v += *(const f4*)(ws + base + (size_t)3 * RG * RB * DD);
            f4 al = *(const f4*)(alpha + dc);
            f4 pv;
            pv.x = v.x >= 0.f ? v.x : al.x * v.x;
            pv.y = v.y >= 0.f ? v.y : al.y * v.y;
            pv.z = v.z >= 0.f ? v.z : al.z * v.z;
            pv.w = v.w >= 0.f ? v.w : al.w * v.w;
            *(f4*)&p[(row - i0) * 128 + dc] = pv;
        }
    }
    __syncthreads();

    const int d  = t & 127;
    const int rq = t >> 7;
    const float bv = b[d];
    float acc[8];
#pragma unroll
    for (int ri = 0; ri < 8; ++ri) acc[ri] = 0.f;
#pragma unroll 8
    for (int k = 0; k < 128; ++k) {
        float wv = Wt[k * 129 + d];
#pragma unroll
        for (int ri = 0; ri < 8; ++ri)
            acc[ri] += p[(rq * 8 + ri) * 128 + k] * wv;
    }
#pragma unroll
    for (int ri = 0; ri < 8; ++ri) {
        int row = i0 + rq * 8 + ri;
        if (row < NN) out[(size_t)row * DD + d] = acc[ri] + bv;
    }
}

extern "C" void kernel_launch(void* const* d_in, const int* in_sizes, int n_in,
                              void* d_out, int out_size, void* d_ws, size_t ws_size,
                              hipStream_t stream) {
    const float* theta = (const float*)d_in[0];
    const float* T     = (const float*)d_in[1];
    const float* x     = (const float*)d_in[2];
    const float* a     = (const float*)d_in[3];
    const float* alpha = (const float*)d_in[4];
    const float* W     = (const float*)d_in[5];
    const float* b     = (const float*)d_in[6];
    float* out = (float*)d_out;
    float* ws  = (float*)d_ws;

    dim3 blk(256);
    dim3 g1(RG * JS);                 // 2500 blocks
    diffuse_spmm<<<g1, blk, 0, stream>>>(theta, T, x, a, ws);

    dim3 g2((NN + 15) / 16);          // 313 blocks
    prelu_linear<<<g2, blk, 0, stream>>>(alpha, W, b, ws, out);
}